// Round 14
// baseline (151.645 us; speedup 1.0000x reference)
//
#include <hip/hip_runtime.h>
#include <cstdint>

#define N_VIS   8192
#define N_ASSOC 4096
#define N_MOTOR 1024
#define IN_DIM  4096
#define T_STEPS 16

// ---------------- encoder matvec (V = x, f32): R13 row-wave LDS structure, CS split ----------
// TWO rows per WAVE; 8 waves/block = 16 rows/block; double-buffered V tile; 1 barrier/iter.
template<int COLS, int CS>
__global__ __launch_bounds__(512, 4) void mv_rowwave_kernel(
        const float* __restrict__ Wg, const float* __restrict__ Vg,
        float* __restrict__ Sp, int nrows) {
    constexpr int F4PR = COLS / 4;
    constexpr int SEG4 = F4PR / CS;
    constexpr int NIT  = SEG4 / 64;
    __shared__ float4 vs[2][16 * 64];
    const int tid  = threadIdx.x;
    const int lane = tid & 63, wv = tid >> 6;
    const int rb   = blockIdx.x / CS;
    const int sp   = blockIdx.x % CS;
    const int j0   = rb * 16 + wv * 2;
    const float4* W4a = (const float4*)Wg + (size_t)j0 * F4PR + (size_t)sp * SEG4;
    const float4* W4b = W4a + F4PR;
    const float4* V4  = (const float4*)Vg + (size_t)sp * SEG4;

    float acc[2][T_STEPS];
#pragma unroll
    for (int t = 0; t < T_STEPS; ++t) { acc[0][t] = 0.f; acc[1][t] = 0.f; }

    {
        int f = tid;
#pragma unroll
        for (int p = 0; p < 2; ++p, f += 512) {
            int t = f >> 6, c = f & 63;
            vs[0][f] = V4[(size_t)t * F4PR + c];
        }
    }
    float4 wa = W4a[lane], wb = W4b[lane];
    __syncthreads();

    int buf = 0;
#pragma unroll 1
    for (int it = 0; it < NIT; ++it) {
        float4 wan = wa, wbn = wb;
        if (it + 1 < NIT) {
            wan = W4a[(it + 1) * 64 + lane];
            wbn = W4b[(it + 1) * 64 + lane];
            int f = tid;
#pragma unroll
            for (int p = 0; p < 2; ++p, f += 512) {
                int t = f >> 6, c = f & 63;
                vs[buf ^ 1][f] = V4[(size_t)t * F4PR + (it + 1) * 64 + c];
            }
        }
#pragma unroll
        for (int t = 0; t < T_STEPS; ++t) {
            float4 v = vs[buf][t * 64 + lane];
            acc[0][t] = fmaf(wa.x, v.x, acc[0][t]);
            acc[0][t] = fmaf(wa.y, v.y, acc[0][t]);
            acc[0][t] = fmaf(wa.z, v.z, acc[0][t]);
            acc[0][t] = fmaf(wa.w, v.w, acc[0][t]);
            acc[1][t] = fmaf(wb.x, v.x, acc[1][t]);
            acc[1][t] = fmaf(wb.y, v.y, acc[1][t]);
            acc[1][t] = fmaf(wb.z, v.z, acc[1][t]);
            acc[1][t] = fmaf(wb.w, v.w, acc[1][t]);
        }
        __syncthreads();
        wa = wan; wb = wbn; buf ^= 1;
    }

#pragma unroll
    for (int t = 0; t < T_STEPS; ++t) {
        float a0 = acc[0][t], a1 = acc[1][t];
        for (int o = 32; o; o >>= 1) {
            a0 += __shfl_down(a0, o, 64);
            a1 += __shfl_down(a1, o, 64);
        }
        acc[0][t] = a0; acc[1][t] = a1;
    }
    if (lane == 0) {
#pragma unroll
        for (int r = 0; r < 2; ++r) {
            float4* So = (float4*)(Sp + ((size_t)sp * nrows + j0 + r) * 16);
#pragma unroll
            for (int q = 0; q < 4; ++q)
                So[q] = make_float4(acc[r][q*4], acc[r][q*4+1], acc[r][q*4+2], acc[r][q*4+3]);
        }
    }
}

// ---------------- spike matvec (V = bitmask): NO LDS, NO barriers, pure streaming ----------
// 2 rows/wave; lane owns 4 columns per iter: loads uint4 of masks + 2 W float4s,
// expands bits in-register (shared across both rows), 128 FMA per iter.
template<int COLS, int CS>
__global__ __launch_bounds__(512, 4) void mv_bits_kernel(
        const float* __restrict__ Wg, const unsigned* __restrict__ mask,
        float* __restrict__ Sp, int nrows) {
    constexpr int F4PR = COLS / 4;
    constexpr int SEG4 = F4PR / CS;
    constexpr int NIT  = SEG4 / 64;
    const int lane = threadIdx.x & 63, wv = threadIdx.x >> 6;
    const int rb   = blockIdx.x / CS;
    const int sp   = blockIdx.x % CS;
    const int j0   = rb * 16 + wv * 2;
    const float4* W4a = (const float4*)Wg + (size_t)j0 * F4PR + (size_t)sp * SEG4;
    const float4* W4b = W4a + F4PR;
    const uint4*  M4  = (const uint4*)mask + (size_t)sp * SEG4;

    float acc0[T_STEPS], acc1[T_STEPS];
#pragma unroll
    for (int t = 0; t < T_STEPS; ++t) { acc0[t] = 0.f; acc1[t] = 0.f; }

#pragma unroll 2
    for (int it = 0; it < NIT; ++it) {
        const int idx = it * 64 + lane;
        float4 wa = W4a[idx];
        float4 wb = W4b[idx];
        uint4  m  = M4[idx];
#pragma unroll
        for (int t = 0; t < T_STEPS; ++t) {
            float bx = (float)((m.x >> t) & 1u);
            float by = (float)((m.y >> t) & 1u);
            float bz = (float)((m.z >> t) & 1u);
            float bw = (float)((m.w >> t) & 1u);
            acc0[t] = fmaf(wa.x, bx, acc0[t]);
            acc0[t] = fmaf(wa.y, by, acc0[t]);
            acc0[t] = fmaf(wa.z, bz, acc0[t]);
            acc0[t] = fmaf(wa.w, bw, acc0[t]);
            acc1[t] = fmaf(wb.x, bx, acc1[t]);
            acc1[t] = fmaf(wb.y, by, acc1[t]);
            acc1[t] = fmaf(wb.z, bz, acc1[t]);
            acc1[t] = fmaf(wb.w, bw, acc1[t]);
        }
    }

#pragma unroll
    for (int t = 0; t < T_STEPS; ++t) {
        float a0 = acc0[t], a1 = acc1[t];
        for (int o = 32; o; o >>= 1) {
            a0 += __shfl_down(a0, o, 64);
            a1 += __shfl_down(a1, o, 64);
        }
        acc0[t] = a0; acc1[t] = a1;
    }
    if (lane == 0) {
        float4* So0 = (float4*)(Sp + ((size_t)sp * nrows + j0) * 16);
        float4* So1 = (float4*)(Sp + ((size_t)sp * nrows + j0 + 1) * 16);
#pragma unroll
        for (int q = 0; q < 4; ++q) {
            So0[q] = make_float4(acc0[q*4], acc0[q*4+1], acc0[q*4+2], acc0[q*4+3]);
            So1[q] = make_float4(acc1[q*4], acc1[q*4+1], acc1[q*4+2], acc1[q*4+3]);
        }
    }
}

// ---------------- visual LIF (sums 2 encoder partials; writes mask only) ----------------
__global__ __launch_bounds__(256) void vlif_kernel(
        const float* __restrict__ S1p, const float* __restrict__ noise,
        const float* __restrict__ b, unsigned* __restrict__ vmask) {
    const int i = blockIdx.x * 256 + threadIdx.x;
    float a[T_STEPS];
#pragma unroll
    for (int t = 0; t < T_STEPS; ++t)
        a[t] = S1p[(size_t)i * 16 + t] + S1p[((size_t)N_VIS + i) * 16 + t];
    const float bb = b[i];
    float v = 0.f;
    unsigned msk = 0;
#pragma unroll
    for (int t = 0; t < T_STEPS; ++t) {
        float logit = a[t] + bb;
        float rate = 1.0f / (1.0f + expf(-logit));
        float u = noise[t * N_VIS + i];
        float ins = (u < rate * 0.3f) ? 1.0f : 0.0f;
        v = v * 0.95f + ins;
        if (v > 1.0f) { msk |= (1u << t); v = 0.f; }
    }
    vmask[i] = msk;
}

// ---------------- K table (+ zeroing of the ovl accumulators) ----------------
__global__ void ktab_kernel(const float* __restrict__ dop, float* __restrict__ K,
                            int* __restrict__ ovl_z) {
    __shared__ float C[256];
    __shared__ float sd[16];
    __shared__ unsigned sg[16];
    const int p = threadIdx.x;
    ovl_z[p] = 0; ovl_z[p + 256] = 0;
    if (p < 16) {
        float d = dop[p];
        sd[p] = d;
        sg[p] = (fabsf(d) > 0.1f) ? 1u : 0u;
    }
    __syncthreads();
    {
        const int s = p >> 4, r = p & 15;
        float c = 0.f;
        if (s >= r) {
            c = 1.f;
            for (int u = r; u < s; ++u) {
                if (sg[u]) c *= 0.5f;
                c *= 0.998f;
            }
        }
        C[p] = c;
    }
    __syncthreads();
    {
        const int t = p >> 4, r = p & 15;
        float kk = 0.f;
        for (int s = r; s < t; ++s)
            if (sg[s]) kk += ((sd[s] * 0.1f) * 0.01f) * C[s * 16 + r];
        K[p] = kk;
    }
}

// ---------------- OVL[r][t] = popcount over mask words of bit_r & bit_t ----------------
__global__ void ovl_kernel(const unsigned* __restrict__ mask, int words_per_block,
                           int* __restrict__ ovl) {
    const int p = threadIdx.x;
    const int r = p >> 4, t = p & 15;
    const unsigned* w = mask + blockIdx.x * words_per_block;
    int c = 0;
    for (int i = 0; i < words_per_block; ++i)
        c += (int)((w[i] >> r) & (w[i] >> t) & 1u);
    atomicAdd(&ovl[p], c);
}

// ---------------- tiny sequential recursion; sums cs partials ----------------
__global__ __launch_bounds__(64) void rec_kernel(
        const float* __restrict__ base, const int* __restrict__ ovl,
        const float* __restrict__ K, unsigned* __restrict__ mask_out,
        float* __restrict__ outp, int out_stride, int n_rows, int cs) {
    __shared__ float KO[256];
    const int tid = threadIdx.x;
    for (int p = tid; p < 256; p += 64) {
        const int t = p >> 4, r = p & 15;
        KO[p] = K[p] * (float)ovl[r * 16 + t];
    }
    __syncthreads();

    const int j = blockIdx.x * 64 + tid;
    float br[T_STEPS];
#pragma unroll
    for (int t = 0; t < T_STEPS; ++t) br[t] = base[(size_t)j * 16 + t];
#pragma unroll 1
    for (int s = 1; s < cs; ++s)
#pragma unroll
        for (int t = 0; t < T_STEPS; ++t)
            br[t] += base[((size_t)s * n_rows + j) * 16 + t];

    float vmem = 0.f;
    unsigned am = 0;
#pragma unroll
    for (int t = 0; t < T_STEPS; ++t) {
        float I = br[t];
        for (int r = 0; r < t; ++r)
            if ((am >> r) & 1u) I += KO[t * 16 + r];
        vmem = vmem * 0.95f + I * 0.1f;
        const bool s = vmem > 1.0f;
        if (s) { vmem = 0.f; am |= (1u << t); }
        if (outp) outp[t * out_stride + j] = s ? 1.0f : 0.0f;
    }
    mask_out[j] = am;
}

extern "C" void kernel_launch(void* const* d_in, const int* in_sizes, int n_in,
                              void* d_out, int out_size, void* d_ws, size_t ws_size,
                              hipStream_t stream) {
    const float* x     = (const float*)d_in[0];   // [16, 4096]
    const float* noise = (const float*)d_in[1];   // [16, 8192]
    const float* dop   = (const float*)d_in[2];   // [16]
    const float* W_enc = (const float*)d_in[3];   // [8192, 4096]
    const float* b_enc = (const float*)d_in[4];   // [8192]
    const float* W_va  = (const float*)d_in[5];   // [4096, 8192]
    const float* W_am  = (const float*)d_in[6];   // [1024, 4096]
    float* out = (float*)d_out;                   // [16, 1024] f32
    (void)in_sizes; (void)n_in; (void)out_size; (void)ws_size;

    char* ws = (char*)d_ws;
    size_t off = 0;
    unsigned* vmask = (unsigned*)(ws + off); off += N_VIS * 4;
    unsigned* amask = (unsigned*)(ws + off); off += N_ASSOC * 4;
    unsigned* mmask = (unsigned*)(ws + off); off += N_MOTOR * 4;
    float*    K     = (float*)(ws + off);    off += 256 * 4;
    int*      ovl_v = (int*)(ws + off);      off += 256 * 4;
    int*      ovl_a = (int*)(ws + off);      off += 256 * 4;
    float*    S1    = (float*)(ws + off);    off += (size_t)2 * N_VIS   * 16 * 4;
    float*    S2    = (float*)(ws + off);    off += (size_t)4 * N_ASSOC * 16 * 4;
    float*    S3    = (float*)(ws + off);    off += (size_t)4 * N_MOTOR * 16 * 4;

    ktab_kernel<<<1, 256, 0, stream>>>(dop, K, ovl_v);   // also zeroes ovl_v/ovl_a
    // visual encoder (x is dense f32): LDS row-wave, CS=2
    mv_rowwave_kernel<IN_DIM, 2><<<(N_VIS / 16) * 2, 512, 0, stream>>>(W_enc, x, S1, N_VIS);
    vlif_kernel<<<N_VIS / 256, 256, 0, stream>>>(S1, noise, b_enc, vmask);
    ovl_kernel<<<32, 256, 0, stream>>>(vmask, N_VIS / 32, ovl_v);
    // assoc layer: barrier-free bit matvec, CS=4
    mv_bits_kernel<N_VIS, 4><<<(N_ASSOC / 16) * 4, 512, 0, stream>>>(W_va, vmask, S2, N_ASSOC);
    rec_kernel<<<N_ASSOC / 64, 64, 0, stream>>>(S2, ovl_v, K, amask, nullptr, 0, N_ASSOC, 4);
    ovl_kernel<<<16, 256, 0, stream>>>(amask, N_ASSOC / 16, ovl_a);
    // motor layer: bit matvec, CS=4
    mv_bits_kernel<N_ASSOC, 4><<<(N_MOTOR / 16) * 4, 512, 0, stream>>>(W_am, amask, S3, N_MOTOR);
    rec_kernel<<<N_MOTOR / 64, 64, 0, stream>>>(S3, ovl_a, K, mmask, out, N_MOTOR, N_MOTOR, 4);
}

// Round 16
// 146.203 us; speedup vs baseline: 1.0372x; 1.0372x over previous
//
#include <hip/hip_runtime.h>
#include <cstdint>

#define N_VIS   8192
#define N_ASSOC 4096
#define N_MOTOR 1024
#define IN_DIM  4096
#define T_STEPS 16

typedef float f32x4 __attribute__((ext_vector_type(4)));   // native vector type for nt loads

__device__ __forceinline__ float4 nt_load4(const float4* p) {
    f32x4 r = __builtin_nontemporal_load((const f32x4*)p);
    return make_float4(r.x, r.y, r.z, r.w);
}

// ---------------- encoder matvec (V = x, f32): row-wave LDS structure, CS split ----------
// TWO rows per WAVE; 8 waves/block = 16 rows/block; double-buffered V tile; 1 barrier/iter.
// W loads are NON-TEMPORAL (stream-once), x/LDS loads cached.
template<int COLS, int CS>
__global__ __launch_bounds__(512, 4) void mv_rowwave_kernel(
        const float* __restrict__ Wg, const float* __restrict__ Vg,
        float* __restrict__ Sp, int nrows) {
    constexpr int F4PR = COLS / 4;
    constexpr int SEG4 = F4PR / CS;
    constexpr int NIT  = SEG4 / 64;
    __shared__ float4 vs[2][16 * 64];
    const int tid  = threadIdx.x;
    const int lane = tid & 63, wv = tid >> 6;
    const int rb   = blockIdx.x / CS;
    const int sp   = blockIdx.x % CS;
    const int j0   = rb * 16 + wv * 2;
    const float4* W4a = (const float4*)Wg + (size_t)j0 * F4PR + (size_t)sp * SEG4;
    const float4* W4b = W4a + F4PR;
    const float4* V4  = (const float4*)Vg + (size_t)sp * SEG4;

    float acc[2][T_STEPS];
#pragma unroll
    for (int t = 0; t < T_STEPS; ++t) { acc[0][t] = 0.f; acc[1][t] = 0.f; }

    {
        int f = tid;
#pragma unroll
        for (int p = 0; p < 2; ++p, f += 512) {
            int t = f >> 6, c = f & 63;
            vs[0][f] = V4[(size_t)t * F4PR + c];
        }
    }
    float4 wa = nt_load4(&W4a[lane]), wb = nt_load4(&W4b[lane]);
    __syncthreads();

    int buf = 0;
#pragma unroll 1
    for (int it = 0; it < NIT; ++it) {
        float4 wan = wa, wbn = wb;
        if (it + 1 < NIT) {
            wan = nt_load4(&W4a[(it + 1) * 64 + lane]);
            wbn = nt_load4(&W4b[(it + 1) * 64 + lane]);
            int f = tid;
#pragma unroll
            for (int p = 0; p < 2; ++p, f += 512) {
                int t = f >> 6, c = f & 63;
                vs[buf ^ 1][f] = V4[(size_t)t * F4PR + (it + 1) * 64 + c];
            }
        }
#pragma unroll
        for (int t = 0; t < T_STEPS; ++t) {
            float4 v = vs[buf][t * 64 + lane];
            acc[0][t] = fmaf(wa.x, v.x, acc[0][t]);
            acc[0][t] = fmaf(wa.y, v.y, acc[0][t]);
            acc[0][t] = fmaf(wa.z, v.z, acc[0][t]);
            acc[0][t] = fmaf(wa.w, v.w, acc[0][t]);
            acc[1][t] = fmaf(wb.x, v.x, acc[1][t]);
            acc[1][t] = fmaf(wb.y, v.y, acc[1][t]);
            acc[1][t] = fmaf(wb.z, v.z, acc[1][t]);
            acc[1][t] = fmaf(wb.w, v.w, acc[1][t]);
        }
        __syncthreads();
        wa = wan; wb = wbn; buf ^= 1;
    }

#pragma unroll
    for (int t = 0; t < T_STEPS; ++t) {
        float a0 = acc[0][t], a1 = acc[1][t];
        for (int o = 32; o; o >>= 1) {
            a0 += __shfl_down(a0, o, 64);
            a1 += __shfl_down(a1, o, 64);
        }
        acc[0][t] = a0; acc[1][t] = a1;
    }
    if (lane == 0) {
#pragma unroll
        for (int r = 0; r < 2; ++r) {
            float4* So = (float4*)(Sp + ((size_t)sp * nrows + j0 + r) * 16);
#pragma unroll
            for (int q = 0; q < 4; ++q)
                So[q] = make_float4(acc[r][q*4], acc[r][q*4+1], acc[r][q*4+2], acc[r][q*4+3]);
        }
    }
}

// ---------------- spike matvec (V = bitmask): NO LDS, NO barriers, nt W streams ----------
template<int COLS, int CS>
__global__ __launch_bounds__(512, 4) void mv_bits_kernel(
        const float* __restrict__ Wg, const unsigned* __restrict__ mask,
        float* __restrict__ Sp, int nrows) {
    constexpr int F4PR = COLS / 4;
    constexpr int SEG4 = F4PR / CS;
    constexpr int NIT  = SEG4 / 64;
    const int lane = threadIdx.x & 63, wv = threadIdx.x >> 6;
    const int rb   = blockIdx.x / CS;
    const int sp   = blockIdx.x % CS;
    const int j0   = rb * 16 + wv * 2;
    const float4* W4a = (const float4*)Wg + (size_t)j0 * F4PR + (size_t)sp * SEG4;
    const float4* W4b = W4a + F4PR;
    const uint4*  M4  = (const uint4*)mask + (size_t)sp * SEG4;

    float acc0[T_STEPS], acc1[T_STEPS];
#pragma unroll
    for (int t = 0; t < T_STEPS; ++t) { acc0[t] = 0.f; acc1[t] = 0.f; }

#pragma unroll 2
    for (int it = 0; it < NIT; ++it) {
        const int idx = it * 64 + lane;
        float4 wa = nt_load4(&W4a[idx]);
        float4 wb = nt_load4(&W4b[idx]);
        uint4  m  = M4[idx];
#pragma unroll
        for (int t = 0; t < T_STEPS; ++t) {
            float bx = (float)((m.x >> t) & 1u);
            float by = (float)((m.y >> t) & 1u);
            float bz = (float)((m.z >> t) & 1u);
            float bw = (float)((m.w >> t) & 1u);
            acc0[t] = fmaf(wa.x, bx, acc0[t]);
            acc0[t] = fmaf(wa.y, by, acc0[t]);
            acc0[t] = fmaf(wa.z, bz, acc0[t]);
            acc0[t] = fmaf(wa.w, bw, acc0[t]);
            acc1[t] = fmaf(wb.x, bx, acc1[t]);
            acc1[t] = fmaf(wb.y, by, acc1[t]);
            acc1[t] = fmaf(wb.z, bz, acc1[t]);
            acc1[t] = fmaf(wb.w, bw, acc1[t]);
        }
    }

#pragma unroll
    for (int t = 0; t < T_STEPS; ++t) {
        float a0 = acc0[t], a1 = acc1[t];
        for (int o = 32; o; o >>= 1) {
            a0 += __shfl_down(a0, o, 64);
            a1 += __shfl_down(a1, o, 64);
        }
        acc0[t] = a0; acc1[t] = a1;
    }
    if (lane == 0) {
        float4* So0 = (float4*)(Sp + ((size_t)sp * nrows + j0) * 16);
        float4* So1 = (float4*)(Sp + ((size_t)sp * nrows + j0 + 1) * 16);
#pragma unroll
        for (int q = 0; q < 4; ++q) {
            So0[q] = make_float4(acc0[q*4], acc0[q*4+1], acc0[q*4+2], acc0[q*4+3]);
            So1[q] = make_float4(acc1[q*4], acc1[q*4+1], acc1[q*4+2], acc1[q*4+3]);
        }
    }
}

// ---------------- visual LIF (sums 2 encoder partials; writes mask only) ----------------
__global__ __launch_bounds__(256) void vlif_kernel(
        const float* __restrict__ S1p, const float* __restrict__ noise,
        const float* __restrict__ b, unsigned* __restrict__ vmask) {
    const int i = blockIdx.x * 256 + threadIdx.x;
    float a[T_STEPS];
#pragma unroll
    for (int t = 0; t < T_STEPS; ++t)
        a[t] = S1p[(size_t)i * 16 + t] + S1p[((size_t)N_VIS + i) * 16 + t];
    const float bb = b[i];
    float v = 0.f;
    unsigned msk = 0;
#pragma unroll
    for (int t = 0; t < T_STEPS; ++t) {
        float logit = a[t] + bb;
        float rate = 1.0f / (1.0f + expf(-logit));
        float u = noise[t * N_VIS + i];
        float ins = (u < rate * 0.3f) ? 1.0f : 0.0f;
        v = v * 0.95f + ins;
        if (v > 1.0f) { msk |= (1u << t); v = 0.f; }
    }
    vmask[i] = msk;
}

// ---------------- K table (+ zeroing of the ovl accumulators) ----------------
__global__ void ktab_kernel(const float* __restrict__ dop, float* __restrict__ K,
                            int* __restrict__ ovl_z) {
    __shared__ float C[256];
    __shared__ float sd[16];
    __shared__ unsigned sg[16];
    const int p = threadIdx.x;
    ovl_z[p] = 0; ovl_z[p + 256] = 0;
    if (p < 16) {
        float d = dop[p];
        sd[p] = d;
        sg[p] = (fabsf(d) > 0.1f) ? 1u : 0u;
    }
    __syncthreads();
    {
        const int s = p >> 4, r = p & 15;
        float c = 0.f;
        if (s >= r) {
            c = 1.f;
            for (int u = r; u < s; ++u) {
                if (sg[u]) c *= 0.5f;
                c *= 0.998f;
            }
        }
        C[p] = c;
    }
    __syncthreads();
    {
        const int t = p >> 4, r = p & 15;
        float kk = 0.f;
        for (int s = r; s < t; ++s)
            if (sg[s]) kk += ((sd[s] * 0.1f) * 0.01f) * C[s * 16 + r];
        K[p] = kk;
    }
}

// ---------------- OVL[r][t] = popcount over mask words of bit_r & bit_t ----------------
__global__ void ovl_kernel(const unsigned* __restrict__ mask, int words_per_block,
                           int* __restrict__ ovl) {
    const int p = threadIdx.x;
    const int r = p >> 4, t = p & 15;
    const unsigned* w = mask + blockIdx.x * words_per_block;
    int c = 0;
    for (int i = 0; i < words_per_block; ++i)
        c += (int)((w[i] >> r) & (w[i] >> t) & 1u);
    atomicAdd(&ovl[p], c);
}

// ---------------- tiny sequential recursion; sums cs partials ----------------
__global__ __launch_bounds__(64) void rec_kernel(
        const float* __restrict__ base, const int* __restrict__ ovl,
        const float* __restrict__ K, unsigned* __restrict__ mask_out,
        float* __restrict__ outp, int out_stride, int n_rows, int cs) {
    __shared__ float KO[256];
    const int tid = threadIdx.x;
    for (int p = tid; p < 256; p += 64) {
        const int t = p >> 4, r = p & 15;
        KO[p] = K[p] * (float)ovl[r * 16 + t];
    }
    __syncthreads();

    const int j = blockIdx.x * 64 + tid;
    float br[T_STEPS];
#pragma unroll
    for (int t = 0; t < T_STEPS; ++t) br[t] = base[(size_t)j * 16 + t];
#pragma unroll 1
    for (int s = 1; s < cs; ++s)
#pragma unroll
        for (int t = 0; t < T_STEPS; ++t)
            br[t] += base[((size_t)s * n_rows + j) * 16 + t];

    float vmem = 0.f;
    unsigned am = 0;
#pragma unroll
    for (int t = 0; t < T_STEPS; ++t) {
        float I = br[t];
        for (int r = 0; r < t; ++r)
            if ((am >> r) & 1u) I += KO[t * 16 + r];
        vmem = vmem * 0.95f + I * 0.1f;
        const bool s = vmem > 1.0f;
        if (s) { vmem = 0.f; am |= (1u << t); }
        if (outp) outp[t * out_stride + j] = s ? 1.0f : 0.0f;
    }
    mask_out[j] = am;
}

extern "C" void kernel_launch(void* const* d_in, const int* in_sizes, int n_in,
                              void* d_out, int out_size, void* d_ws, size_t ws_size,
                              hipStream_t stream) {
    const float* x     = (const float*)d_in[0];   // [16, 4096]
    const float* noise = (const float*)d_in[1];   // [16, 8192]
    const float* dop   = (const float*)d_in[2];   // [16]
    const float* W_enc = (const float*)d_in[3];   // [8192, 4096]
    const float* b_enc = (const float*)d_in[4];   // [8192]
    const float* W_va  = (const float*)d_in[5];   // [4096, 8192]
    const float* W_am  = (const float*)d_in[6];   // [1024, 4096]
    float* out = (float*)d_out;                   // [16, 1024] f32
    (void)in_sizes; (void)n_in; (void)out_size; (void)ws_size;

    char* ws = (char*)d_ws;
    size_t off = 0;
    unsigned* vmask = (unsigned*)(ws + off); off += N_VIS * 4;
    unsigned* amask = (unsigned*)(ws + off); off += N_ASSOC * 4;
    unsigned* mmask = (unsigned*)(ws + off); off += N_MOTOR * 4;
    float*    K     = (float*)(ws + off);    off += 256 * 4;
    int*      ovl_v = (int*)(ws + off);      off += 256 * 4;
    int*      ovl_a = (int*)(ws + off);      off += 256 * 4;
    float*    S1    = (float*)(ws + off);    off += (size_t)2 * N_VIS   * 16 * 4;
    float*    S2    = (float*)(ws + off);    off += (size_t)4 * N_ASSOC * 16 * 4;
    float*    S3    = (float*)(ws + off);    off += (size_t)4 * N_MOTOR * 16 * 4;

    ktab_kernel<<<1, 256, 0, stream>>>(dop, K, ovl_v);   // also zeroes ovl_v/ovl_a
    // visual encoder (x is dense f32): LDS row-wave, CS=2, nt W stream
    mv_rowwave_kernel<IN_DIM, 2><<<(N_VIS / 16) * 2, 512, 0, stream>>>(W_enc, x, S1, N_VIS);
    vlif_kernel<<<N_VIS / 256, 256, 0, stream>>>(S1, noise, b_enc, vmask);
    ovl_kernel<<<32, 256, 0, stream>>>(vmask, N_VIS / 32, ovl_v);
    // assoc layer: barrier-free bit matvec, CS=4, nt W stream
    mv_bits_kernel<N_VIS, 4><<<(N_ASSOC / 16) * 4, 512, 0, stream>>>(W_va, vmask, S2, N_ASSOC);
    rec_kernel<<<N_ASSOC / 64, 64, 0, stream>>>(S2, ovl_v, K, amask, nullptr, 0, N_ASSOC, 4);
    ovl_kernel<<<16, 256, 0, stream>>>(amask, N_ASSOC / 16, ovl_a);
    // motor layer: bit matvec, CS=4, nt W stream
    mv_bits_kernel<N_ASSOC, 4><<<(N_MOTOR / 16) * 4, 512, 0, stream>>>(W_am, amask, S3, N_MOTOR);
    rec_kernel<<<N_MOTOR / 64, 64, 0, stream>>>(S3, ovl_a, K, mmask, out, N_MOTOR, N_MOTOR, 4);
}

// Round 17
// 140.438 us; speedup vs baseline: 1.0798x; 1.0410x over previous
//
#include <hip/hip_runtime.h>
#include <cstdint>

#define N_VIS   8192
#define N_ASSOC 4096
#define N_MOTOR 1024
#define IN_DIM  4096
#define T_STEPS 16

typedef float f32x4 __attribute__((ext_vector_type(4)));

__device__ __forceinline__ float4 nt_load4(const float4* p) {
    f32x4 r = __builtin_nontemporal_load((const f32x4*)p);
    return make_float4(r.x, r.y, r.z, r.w);
}

// ---------------- K table (+ zeroing of both ovl accumulators) ----------------
__global__ void ktab_kernel(const float* __restrict__ dop, float* __restrict__ K,
                            int* __restrict__ ovl_z) {
    __shared__ float C[256];
    __shared__ float sd[16];
    __shared__ unsigned sg[16];
    const int p = threadIdx.x;
    ovl_z[p] = 0; ovl_z[p + 256] = 0;
    if (p < 16) {
        float d = dop[p];
        sd[p] = d;
        sg[p] = (fabsf(d) > 0.1f) ? 1u : 0u;
    }
    __syncthreads();
    {
        const int s = p >> 4, r = p & 15;
        float c = 0.f;
        if (s >= r) {
            c = 1.f;
            for (int u = r; u < s; ++u) {
                if (sg[u]) c *= 0.5f;
                c *= 0.998f;
            }
        }
        C[p] = c;
    }
    __syncthreads();
    {
        const int t = p >> 4, r = p & 15;
        float kk = 0.f;
        for (int s = r; s < t; ++s)
            if (sg[s]) kk += ((sd[s] * 0.1f) * 0.01f) * C[s * 16 + r];
        K[p] = kk;
    }
}

// ---- encoder fused: matvec (x staged in LDS) + visual LIF + vmask + OVL_v atomics ----
// 512 threads = 8 waves x 2 rows = 16 rows/block; grid 512.
__global__ __launch_bounds__(512, 4) void enc_fused_kernel(
        const float* __restrict__ Wg, const float* __restrict__ xg,
        const float* __restrict__ noise, const float* __restrict__ b,
        unsigned* __restrict__ vmask, int* __restrict__ ovl_v) {
    constexpr int F4PR = IN_DIM / 4;   // 1024
    constexpr int NIT  = F4PR / 64;    // 16
    __shared__ float4 vs[2][16 * 64];
    __shared__ unsigned smask[16];
    const int tid  = threadIdx.x;
    const int lane = tid & 63, wv = tid >> 6;
    const int j0   = blockIdx.x * 16 + wv * 2;
    const float4* W4a = (const float4*)Wg + (size_t)j0 * F4PR;
    const float4* W4b = W4a + F4PR;
    const float4* V4  = (const float4*)xg;

    float acc0[T_STEPS], acc1[T_STEPS];
#pragma unroll
    for (int t = 0; t < T_STEPS; ++t) { acc0[t] = 0.f; acc1[t] = 0.f; }

    {
        int f = tid;
#pragma unroll
        for (int p = 0; p < 2; ++p, f += 512) {
            int t = f >> 6, c = f & 63;
            vs[0][f] = V4[(size_t)t * F4PR + c];
        }
    }
    float4 wa = nt_load4(&W4a[lane]), wb = nt_load4(&W4b[lane]);
    __syncthreads();

    int buf = 0;
#pragma unroll 1
    for (int it = 0; it < NIT; ++it) {
        float4 wan = wa, wbn = wb;
        if (it + 1 < NIT) {
            wan = nt_load4(&W4a[(it + 1) * 64 + lane]);
            wbn = nt_load4(&W4b[(it + 1) * 64 + lane]);
            int f = tid;
#pragma unroll
            for (int p = 0; p < 2; ++p, f += 512) {
                int t = f >> 6, c = f & 63;
                vs[buf ^ 1][f] = V4[(size_t)t * F4PR + (it + 1) * 64 + c];
            }
        }
#pragma unroll
        for (int t = 0; t < T_STEPS; ++t) {
            float4 v = vs[buf][t * 64 + lane];
            acc0[t] = fmaf(wa.x, v.x, acc0[t]);
            acc0[t] = fmaf(wa.y, v.y, acc0[t]);
            acc0[t] = fmaf(wa.z, v.z, acc0[t]);
            acc0[t] = fmaf(wa.w, v.w, acc0[t]);
            acc1[t] = fmaf(wb.x, v.x, acc1[t]);
            acc1[t] = fmaf(wb.y, v.y, acc1[t]);
            acc1[t] = fmaf(wb.z, v.z, acc1[t]);
            acc1[t] = fmaf(wb.w, v.w, acc1[t]);
        }
        __syncthreads();
        wa = wan; wb = wbn; buf ^= 1;
    }

#pragma unroll
    for (int t = 0; t < T_STEPS; ++t) {
        float a0 = acc0[t], a1 = acc1[t];
        for (int o = 32; o; o >>= 1) {
            a0 += __shfl_down(a0, o, 64);
            a1 += __shfl_down(a1, o, 64);
        }
        acc0[t] = a0; acc1[t] = a1;
    }
    if (lane == 0) {
        auto do_row = [&](int i, const float (&a)[T_STEPS]) -> unsigned {
            float bb = b[i];
            float v = 0.f;
            unsigned msk = 0;
#pragma unroll
            for (int t = 0; t < T_STEPS; ++t) {
                float logit = a[t] + bb;
                float rate = 1.0f / (1.0f + expf(-logit));
                float u = noise[t * N_VIS + i];
                float ins = (u < rate * 0.3f) ? 1.0f : 0.0f;
                v = v * 0.95f + ins;
                if (v > 1.0f) { msk |= (1u << t); v = 0.f; }
            }
            vmask[i] = msk;
            return msk;
        };
        smask[wv * 2]     = do_row(j0, acc0);
        smask[wv * 2 + 1] = do_row(j0 + 1, acc1);
    }
    __syncthreads();
    if (tid < 256) {
        const int r = tid >> 4, t = tid & 15;
        int c = 0;
#pragma unroll
        for (int q = 0; q < 16; ++q)
            c += (int)((smask[q] >> r) & (smask[q] >> t) & 1u);
        if (c) atomicAdd(&ovl_v[tid], c);
    }
}

// ---- layer fused: bit matvec + inline LIF/rec recursion (+ optional OVL_out, out write) ----
// NT threads = NT/64 waves x 2 rows; wave owns its rows end-to-end (no cross-wave reduce).
template<int COLS, int NT, int WRITE_OVL>
__global__ __launch_bounds__(NT, 4) void layer_fused_kernel(
        const float* __restrict__ Wg, const unsigned* __restrict__ mask,
        const float* __restrict__ K, const int* __restrict__ ovl_in,
        unsigned* __restrict__ mask_out, int* __restrict__ ovl_out,
        float* __restrict__ outp, int out_stride) {
    constexpr int F4PR = COLS / 4;
    constexpr int NIT  = F4PR / 64;
    constexpr int ROWS = (NT / 64) * 2;
    __shared__ float KO[256];
    __shared__ unsigned smask[ROWS];
    const int tid  = threadIdx.x;
    const int lane = tid & 63, wv = tid >> 6;
    const int j0   = blockIdx.x * ROWS + wv * 2;

    for (int p = tid; p < 256; p += NT)
        KO[p] = K[p] * (float)ovl_in[(p & 15) * 16 + (p >> 4)];   // KO[t*16+r] = K * OVL[r][t]
    __syncthreads();

    const float4* W4a = (const float4*)Wg + (size_t)j0 * F4PR;
    const float4* W4b = W4a + F4PR;
    const uint4*  M4  = (const uint4*)mask;

    float acc0[T_STEPS], acc1[T_STEPS];
#pragma unroll
    for (int t = 0; t < T_STEPS; ++t) { acc0[t] = 0.f; acc1[t] = 0.f; }

#pragma unroll 2
    for (int it = 0; it < NIT; ++it) {
        const int idx = it * 64 + lane;
        float4 wa = nt_load4(&W4a[idx]);
        float4 wb = nt_load4(&W4b[idx]);
        uint4  m  = M4[idx];
#pragma unroll
        for (int t = 0; t < T_STEPS; ++t) {
            float bx = (float)((m.x >> t) & 1u);
            float by = (float)((m.y >> t) & 1u);
            float bz = (float)((m.z >> t) & 1u);
            float bw = (float)((m.w >> t) & 1u);
            acc0[t] = fmaf(wa.x, bx, acc0[t]);
            acc0[t] = fmaf(wa.y, by, acc0[t]);
            acc0[t] = fmaf(wa.z, bz, acc0[t]);
            acc0[t] = fmaf(wa.w, bw, acc0[t]);
            acc1[t] = fmaf(wb.x, bx, acc1[t]);
            acc1[t] = fmaf(wb.y, by, acc1[t]);
            acc1[t] = fmaf(wb.z, bz, acc1[t]);
            acc1[t] = fmaf(wb.w, bw, acc1[t]);
        }
    }

#pragma unroll
    for (int t = 0; t < T_STEPS; ++t) {
        float a0 = acc0[t], a1 = acc1[t];
        for (int o = 32; o; o >>= 1) {
            a0 += __shfl_down(a0, o, 64);
            a1 += __shfl_down(a1, o, 64);
        }
        acc0[t] = a0; acc1[t] = a1;
    }

    if (lane == 0) {
        auto do_rec = [&](int j, const float (&br)[T_STEPS]) -> unsigned {
            float vmem = 0.f;
            unsigned am = 0;
#pragma unroll
            for (int t = 0; t < T_STEPS; ++t) {
                float I = br[t];
                for (int r = 0; r < t; ++r)
                    if ((am >> r) & 1u) I += KO[t * 16 + r];
                vmem = vmem * 0.95f + I * 0.1f;
                const bool s = vmem > 1.0f;
                if (s) { vmem = 0.f; am |= (1u << t); }
                if (outp) outp[t * out_stride + j] = s ? 1.0f : 0.0f;
            }
            if (mask_out) mask_out[j] = am;
            return am;
        };
        smask[wv * 2]     = do_rec(j0, acc0);
        smask[wv * 2 + 1] = do_rec(j0 + 1, acc1);
    }
    if (WRITE_OVL) {
        __syncthreads();
        for (int p = tid; p < 256; p += NT) {
            const int r = p >> 4, t = p & 15;
            int c = 0;
#pragma unroll
            for (int q = 0; q < ROWS; ++q)
                c += (int)((smask[q] >> r) & (smask[q] >> t) & 1u);
            if (c) atomicAdd(&ovl_out[p], c);
        }
    }
}

extern "C" void kernel_launch(void* const* d_in, const int* in_sizes, int n_in,
                              void* d_out, int out_size, void* d_ws, size_t ws_size,
                              hipStream_t stream) {
    const float* x     = (const float*)d_in[0];   // [16, 4096]
    const float* noise = (const float*)d_in[1];   // [16, 8192]
    const float* dop   = (const float*)d_in[2];   // [16]
    const float* W_enc = (const float*)d_in[3];   // [8192, 4096]
    const float* b_enc = (const float*)d_in[4];   // [8192]
    const float* W_va  = (const float*)d_in[5];   // [4096, 8192]
    const float* W_am  = (const float*)d_in[6];   // [1024, 4096]
    float* out = (float*)d_out;                   // [16, 1024] f32
    (void)in_sizes; (void)n_in; (void)out_size; (void)ws_size;

    char* ws = (char*)d_ws;
    size_t off = 0;
    unsigned* vmask = (unsigned*)(ws + off); off += N_VIS * 4;
    unsigned* amask = (unsigned*)(ws + off); off += N_ASSOC * 4;
    float*    K     = (float*)(ws + off);    off += 256 * 4;
    int*      ovl_v = (int*)(ws + off);      off += 256 * 4;
    int*      ovl_a = (int*)(ws + off);      off += 256 * 4;

    // 1: K table + zero ovl_v/ovl_a (adjacent)
    ktab_kernel<<<1, 256, 0, stream>>>(dop, K, ovl_v);
    // 2: encoder matvec + visual LIF + vmask + OVL_v
    enc_fused_kernel<<<N_VIS / 16, 512, 0, stream>>>(W_enc, x, noise, b_enc, vmask, ovl_v);
    // 3: assoc matvec + rec + amask + OVL_a
    layer_fused_kernel<N_VIS, 256, 1><<<N_ASSOC / 8, 256, 0, stream>>>(
        W_va, vmask, K, ovl_v, amask, ovl_a, nullptr, 0);
    // 4: motor matvec + rec + output
    layer_fused_kernel<N_ASSOC, 128, 0><<<N_MOTOR / 4, 128, 0, stream>>>(
        W_am, amask, K, ovl_a, nullptr, nullptr, out, N_MOTOR);
}